// Round 2
// baseline (289.125 us; speedup 1.0000x reference)
//
#include <hip/hip_runtime.h>
#include <math.h>

// MoE top-2 router. Round 5: LDS-free register-pipelined fused kernel.
// Key insight: the mfma_f32_16x16x32_bf16 A/B fragment layouts are directly
// loadable from global memory (A: 8 contiguous fp32 of one token row;
// B: 8 contiguous bf16 of one expert row), so the LDS staging + barriers of
// round 4 (which forced a vmcnt(0) drain per chunk at 1 wave/SIMD -> 790 GB/s
// latency-bound) are removed entirely. Each wave owns 16 tokens and runs a
// free-running k-loop with a 4-deep register rotation (static names) for both
// x and W fragments: ~3 k-steps of loads always in flight, no barriers, no
// vmcnt(0) in the loop. Epilogue (in-register softmax + top-2) unchanged from
// the verified round-4 kernel.
//
// x: [16384, 2048] fp32, W: [64, 2048] fp32.
// outputs (concat, fp32): mask [T,64], idx-as-float [T,2],
//                         router_probs [T,64], probs [T,64]

#define D_DIM 2048
#define E_DIM 64

typedef __bf16 bf16x8 __attribute__((ext_vector_type(8)));
typedef unsigned short us8 __attribute__((ext_vector_type(8)));
typedef float f32x4 __attribute__((ext_vector_type(4)));

static __device__ __forceinline__ unsigned short f2bf(float f) {
    unsigned int u = __float_as_uint(f);
    u += 0x7fffu + ((u >> 16) & 1u);   // RNE
    return (unsigned short)(u >> 16);
}
static __device__ __forceinline__ float bf2f(unsigned short h) {
    return __uint_as_float(((unsigned int)h) << 16);
}
static __device__ __forceinline__ void split4(const float4 v, ushort4* h, ushort4* l) {
    h->x = f2bf(v.x); l->x = f2bf(v.x - bf2f(h->x));
    h->y = f2bf(v.y); l->y = f2bf(v.y - bf2f(h->y));
    h->z = f2bf(v.z); l->z = f2bf(v.z - bf2f(h->z));
    h->w = f2bf(v.w); l->w = f2bf(v.w - bf2f(h->w));
}

// ---- pre-convert W (64x2048 fp32) -> bf16 hi/lo, linear layout ----
__global__ __launch_bounds__(256, 1) void convert_w(
    const float4* __restrict__ W4, unsigned short* __restrict__ WH,
    unsigned short* __restrict__ WL)
{
    int i = blockIdx.x * 256 + threadIdx.x;   // float4 index
    float4 v = W4[i];
    ushort4 h, l;
    split4(v, &h, &l);
    *(ushort4*)&WH[i * 4] = h;
    *(ushort4*)&WL[i * 4] = l;
}

// ---- register fragment sets (static names only: rule #20) ----
struct XS { float4 a, b; };                       // 8 fp32 of one token row
struct WS { bf16x8 h0, h1, h2, h3, l0, l1, l2, l3; };  // B frags, 4 expert tiles

static __device__ __forceinline__ void ldx(XS& s, const float* p) {
    s.a = *(const float4*)(p);
    s.b = *(const float4*)(p + 4);
}
static __device__ __forceinline__ void ldw(WS& s, const unsigned short* ph,
                                           const unsigned short* pl) {
    s.h0 = *(const bf16x8*)(ph);
    s.h1 = *(const bf16x8*)(ph + 16 * D_DIM);
    s.h2 = *(const bf16x8*)(ph + 32 * D_DIM);
    s.h3 = *(const bf16x8*)(ph + 48 * D_DIM);
    s.l0 = *(const bf16x8*)(pl);
    s.l1 = *(const bf16x8*)(pl + 16 * D_DIM);
    s.l2 = *(const bf16x8*)(pl + 32 * D_DIM);
    s.l3 = *(const bf16x8*)(pl + 48 * D_DIM);
}

static __device__ __forceinline__ void comp(const XS& xv, const WS& w, f32x4* acc) {
    ushort4 h0, l0, h1, l1;
    split4(xv.a, &h0, &l0);
    split4(xv.b, &h1, &l1);
    union { us8 u; bf16x8 b; } ua, ul;
    ua.u = (us8){h0.x, h0.y, h0.z, h0.w, h1.x, h1.y, h1.z, h1.w};
    ul.u = (us8){l0.x, l0.y, l0.z, l0.w, l1.x, l1.y, l1.z, l1.w};
    acc[0] = __builtin_amdgcn_mfma_f32_16x16x32_bf16(ua.b, w.h0, acc[0], 0, 0, 0);
    acc[0] = __builtin_amdgcn_mfma_f32_16x16x32_bf16(ul.b, w.h0, acc[0], 0, 0, 0);
    acc[0] = __builtin_amdgcn_mfma_f32_16x16x32_bf16(ua.b, w.l0, acc[0], 0, 0, 0);
    acc[1] = __builtin_amdgcn_mfma_f32_16x16x32_bf16(ua.b, w.h1, acc[1], 0, 0, 0);
    acc[1] = __builtin_amdgcn_mfma_f32_16x16x32_bf16(ul.b, w.h1, acc[1], 0, 0, 0);
    acc[1] = __builtin_amdgcn_mfma_f32_16x16x32_bf16(ua.b, w.l1, acc[1], 0, 0, 0);
    acc[2] = __builtin_amdgcn_mfma_f32_16x16x32_bf16(ua.b, w.h2, acc[2], 0, 0, 0);
    acc[2] = __builtin_amdgcn_mfma_f32_16x16x32_bf16(ul.b, w.h2, acc[2], 0, 0, 0);
    acc[2] = __builtin_amdgcn_mfma_f32_16x16x32_bf16(ua.b, w.l2, acc[2], 0, 0, 0);
    acc[3] = __builtin_amdgcn_mfma_f32_16x16x32_bf16(ua.b, w.h3, acc[3], 0, 0, 0);
    acc[3] = __builtin_amdgcn_mfma_f32_16x16x32_bf16(ul.b, w.h3, acc[3], 0, 0, 0);
    acc[3] = __builtin_amdgcn_mfma_f32_16x16x32_bf16(ua.b, w.l3, acc[3], 0, 0, 0);
}

// ---- fused GEMM + softmax + top-2 + outputs; 1 wave per 16 tokens ----
__global__ __launch_bounds__(64, 1) void router_fused(
    const float* __restrict__ x,
    const unsigned short* __restrict__ WHg, const unsigned short* __restrict__ WLg,
    float* __restrict__ mask_out, float* __restrict__ idx_out,
    float* __restrict__ rp_out, float* __restrict__ probs_out)
{
    const int lane = threadIdx.x;
    const int quad = lane >> 4;
    const int l16  = lane & 15;
    const int t0   = blockIdx.x << 4;

    // A-fragment base: token row l16, k-offset quad*8 (8 contiguous fp32).
    // B-fragment base: expert row l16 (+n*16), k-offset quad*8 (8 contig bf16).
    const float*          xp  = x   + (size_t)(t0 + l16) * D_DIM + quad * 8;
    const unsigned short* whp = WHg + (size_t)l16 * D_DIM + quad * 8;
    const unsigned short* wlp = WLg + (size_t)l16 * D_DIM + quad * 8;

    f32x4 acc[4];
    #pragma unroll
    for (int n = 0; n < 4; ++n) { f32x4 z = {0.f, 0.f, 0.f, 0.f}; acc[n] = z; }

    // 4-deep register rotation: x_i / w_i hold k-step jb+i.
    // 64 k-steps of 32 elements; element offset = step * 32 (same count for
    // fp32 x and bf16 W).
    XS x0, x1, x2, x3;
    WS w0, w1, w2, w3;
    ldx(x0, xp +  0); ldw(w0, whp +  0, wlp +  0);
    ldx(x1, xp + 32); ldw(w1, whp + 32, wlp + 32);
    ldx(x2, xp + 64); ldw(w2, whp + 64, wlp + 64);
    ldx(x3, xp + 96); ldw(w3, whp + 96, wlp + 96);

    for (int jb = 0; jb < 64; jb += 4) {
        // prefetch offsets, clamped at the tail (redundant re-loads, harmless)
        const int p4 = min(jb + 4, 63) << 5;
        const int p5 = min(jb + 5, 63) << 5;
        const int p6 = min(jb + 6, 63) << 5;
        const int p7 = min(jb + 7, 63) << 5;
        comp(x0, w0, acc); ldx(x0, xp + p4); ldw(w0, whp + p4, wlp + p4);
        comp(x1, w1, acc); ldx(x1, xp + p5); ldw(w1, whp + p5, wlp + p5);
        comp(x2, w2, acc); ldx(x2, xp + p6); ldw(w2, whp + p6, wlp + p6);
        comp(x3, w3, acc); ldx(x3, xp + p7); ldw(w3, whp + p7, wlp + p7);
    }

    // ---- epilogue: softmax + top-2 entirely in-register (verified R4) ----
    // acc[n][r] = logit(token = quad*4 + r, expert = n*16 + l16).
    #pragma unroll
    for (int r = 0; r < 4; ++r) {
        const int t = t0 + quad * 4 + r;
        const float v0 = acc[0][r], v1 = acc[1][r], v2 = acc[2][r], v3 = acc[3][r];

        // argmax, lower-index tie-break (matches jax.lax.top_k)
        float bv = v0; int bi = l16;
        if (v1 > bv) { bv = v1; bi = 16 + l16; }
        if (v2 > bv) { bv = v2; bi = 32 + l16; }
        if (v3 > bv) { bv = v3; bi = 48 + l16; }
        #pragma unroll
        for (int off = 1; off < 16; off <<= 1) {
            float ov = __shfl_xor(bv, off);
            int   oi = __shfl_xor(bi, off);
            bool take = (ov > bv) || (ov == bv && oi < bi);
            bv = take ? ov : bv;
            bi = take ? oi : bi;
        }
        const float m = bv; const int i1 = bi;

        const float p0 = __expf(v0 - m), p1 = __expf(v1 - m);
        const float p2 = __expf(v2 - m), p3 = __expf(v3 - m);
        float s = p0 + p1 + p2 + p3;
        #pragma unroll
        for (int off = 1; off < 16; off <<= 1) s += __shfl_xor(s, off);

        // second argmax excluding i1
        const float u0 = (i1 == l16)      ? -INFINITY : v0;
        const float u1 = (i1 == 16 + l16) ? -INFINITY : v1;
        const float u2 = (i1 == 32 + l16) ? -INFINITY : v2;
        const float u3 = (i1 == 48 + l16) ? -INFINITY : v3;
        float cv = u0; int ci = l16;
        if (u1 > cv) { cv = u1; ci = 16 + l16; }
        if (u2 > cv) { cv = u2; ci = 32 + l16; }
        if (u3 > cv) { cv = u3; ci = 48 + l16; }
        #pragma unroll
        for (int off = 1; off < 16; off <<= 1) {
            float ov = __shfl_xor(cv, off);
            int   oi = __shfl_xor(ci, off);
            bool take = (ov > cv) || (ov == cv && oi < ci);
            cv = take ? ov : cv;
            ci = take ? oi : ci;
        }
        const int i2 = ci;

        const float inv_s = 1.f / s;
        const float q0 = p0 * inv_s, q1 = p1 * inv_s;
        const float q2 = p2 * inv_s, q3 = p3 * inv_s;
        const bool m0 = (l16 == i1)      || (l16 == i2);
        const bool m1 = (16 + l16 == i1) || (16 + l16 == i2);
        const bool m2 = (32 + l16 == i1) || (32 + l16 == i2);
        const bool m3 = (48 + l16 == i1) || (48 + l16 == i2);

        float pd = (m0 ? q0 : 0.f) + (m1 ? q1 : 0.f)
                 + (m2 ? q2 : 0.f) + (m3 ? q3 : 0.f);
        #pragma unroll
        for (int off = 1; off < 16; off <<= 1) pd += __shfl_xor(pd, off);
        const float ipd = 1.f / pd;

        const size_t base = (size_t)t * 64 + l16;
        probs_out[base]      = q0;
        probs_out[base + 16] = q1;
        probs_out[base + 32] = q2;
        probs_out[base + 48] = q3;
        mask_out[base]      = m0 ? 1.f : 0.f;
        mask_out[base + 16] = m1 ? 1.f : 0.f;
        mask_out[base + 32] = m2 ? 1.f : 0.f;
        mask_out[base + 48] = m3 ? 1.f : 0.f;
        rp_out[base]      = m0 ? q0 * ipd : 0.f;
        rp_out[base + 16] = m1 ? q1 * ipd : 0.f;
        rp_out[base + 32] = m2 ? q2 * ipd : 0.f;
        rp_out[base + 48] = m3 ? q3 * ipd : 0.f;
        if (l16 == 0) {
            idx_out[(size_t)t * 2]     = (float)i1;
            idx_out[(size_t)t * 2 + 1] = (float)i2;
        }
    }
}

extern "C" void kernel_launch(void* const* d_in, const int* in_sizes, int n_in,
                              void* d_out, int out_size, void* d_ws, size_t ws_size,
                              hipStream_t stream) {
    const float* x = (const float*)d_in[0];
    const float* W = (const float*)d_in[1];
    float* out = (float*)d_out;

    const int T  = in_sizes[0] / D_DIM;     // 16384 tokens
    const int WN = in_sizes[1];             // 131072 elements

    unsigned short* WH = (unsigned short*)d_ws;
    unsigned short* WL = WH + WN;           // total ws use: 512 KB

    float* mask_out  = out;
    float* idx_out   = out + (size_t)T * E_DIM;
    float* rp_out    = idx_out + (size_t)T * 2;
    float* probs_out = rp_out + (size_t)T * E_DIM;

    convert_w<<<dim3(WN / 1024), dim3(256), 0, stream>>>((const float4*)W, WH, WL);
    router_fused<<<dim3(T / 16), dim3(64), 0, stream>>>(
        x, WH, WL, mask_out, idx_out, rp_out, probs_out);
}

// Round 3
// 221.279 us; speedup vs baseline: 1.3066x; 1.3066x over previous
//
#include <hip/hip_runtime.h>
#include <math.h>

// MoE top-2 router. Round 6: round-4 skeleton (global_load_lds dbuf pipeline,
// verified) retiled for concurrency. Round 4 was latency-bound at 1 block/CU
// (grid=256): every chunk's vmcnt(0)+barrier drain stalled the CU. Round 5's
// register rotation was collapsed by the compiler (VGPR=88 proves it).
// Fix: 16-token blocks -> grid=1024 = 4 blocks/CU (LDS 40KB, bounds(256,4)).
// Each wave computes one 16-expert tile over the shared 16-token X tile;
// epilogue exchanges logit slices through LDS, then the verified 64-lane
// reduce handles softmax/top-2 per token.
//
// x: [16384, 2048] fp32, W: [64, 2048] fp32.
// outputs (concat, fp32): mask [T,64], idx-as-float [T,2],
//                         router_probs [T,64], probs [T,64]

#define D_DIM 2048
#define E_DIM 64

typedef __bf16 bf16x8 __attribute__((ext_vector_type(8)));
typedef unsigned short us8 __attribute__((ext_vector_type(8)));
typedef float f32x4 __attribute__((ext_vector_type(4)));

static __device__ __forceinline__ unsigned short f2bf(float f) {
    unsigned int u = __float_as_uint(f);
    u += 0x7fffu + ((u >> 16) & 1u);   // RNE
    return (unsigned short)(u >> 16);
}
static __device__ __forceinline__ float bf2f(unsigned short h) {
    return __uint_as_float(((unsigned int)h) << 16);
}
static __device__ __forceinline__ void split4(const float4 v, ushort4* h, ushort4* l) {
    h->x = f2bf(v.x); l->x = f2bf(v.x - bf2f(h->x));
    h->y = f2bf(v.y); l->y = f2bf(v.y - bf2f(h->y));
    h->z = f2bf(v.z); l->z = f2bf(v.z - bf2f(h->z));
    h->w = f2bf(v.w); l->w = f2bf(v.w - bf2f(h->w));
}

static __device__ __forceinline__ void gld_lds16(const void* g, void* l) {
    __builtin_amdgcn_global_load_lds(
        (const __attribute__((address_space(1))) unsigned int*)g,
        (__attribute__((address_space(3))) unsigned int*)l,
        16, 0, 0);
}

// ---- pre-convert W (64x2048 fp32) -> bf16 hi/lo, linear layout ----
__global__ __launch_bounds__(256, 1) void convert_w(
    const float4* __restrict__ W4, unsigned short* __restrict__ WH,
    unsigned short* __restrict__ WL)
{
    int i = blockIdx.x * 256 + threadIdx.x;   // float4 index
    float4 v = W4[i];
    ushort4 h, l;
    split4(v, &h, &l);
    *(ushort4*)&WH[i * 4] = h;
    *(ushort4*)&WL[i * 4] = l;
}

// ---- fused GEMM + softmax + top-2 + outputs ----
// block = 16 tokens x 64 experts x K=2048; 256 threads (4 waves);
// wave wv computes expert tile [wv*16, wv*16+16) for all 16 tokens.
__global__ __launch_bounds__(256, 4) void router_fused(
    const float* __restrict__ x,
    const unsigned short* __restrict__ WHg, const unsigned short* __restrict__ WLg,
    float* __restrict__ mask_out, float* __restrict__ idx_out,
    float* __restrict__ rp_out, float* __restrict__ probs_out)
{
    // 16B-slot-swizzled LDS tiles, double-buffered (40 KB -> 4 blocks/CU)
    __shared__ __align__(16) float          XF [2][16 * 64];  // 2x 4 KB fp32 x
    __shared__ __align__(16) unsigned short WHs[2][64 * 64];  // 2x 8 KB
    __shared__ __align__(16) unsigned short WLs[2][64 * 64];  // 2x 8 KB

    const int tid  = threadIdx.x;
    const int lane = tid & 63;
    const int wv   = tid >> 6;
    const int quad = lane >> 4;
    const int l16  = lane & 15;

    const int t0  = blockIdx.x << 4;
    const int NCH = D_DIM >> 6;               // 32 chunks of 64 k

    f32x4 acc = {0.f, 0.f, 0.f, 0.f};

    // staging-lane constants
    const int xrow = tid >> 4;                       // x row 0..15
    const int xcg  = (tid & 15) ^ (xrow & 15);       // swizzled float4 col
    const int we   = wv * 8 + (lane >> 3);           // + 32*i2 -> W expert row
    const int wo   = lane & 7;                       // W k-octet before swizzle

    // ---- prologue: stage chunk 0 into buffer 0 ----
    {
        gld_lds16(x + (size_t)(t0 + xrow) * D_DIM + xcg * 4,
                  &XF[0][(wv * 64) * 4]);
        #pragma unroll
        for (int i2 = 0; i2 < 2; ++i2) {
            int e  = i2 * 32 + we;
            int og = wo ^ (e & 7);
            gld_lds16(WHg + (size_t)e * D_DIM + og * 8,
                      &WHs[0][(i2 * 256 + wv * 64) * 8]);
            gld_lds16(WLg + (size_t)e * D_DIM + og * 8,
                      &WLs[0][(i2 * 256 + wv * 64) * 8]);
        }
    }
    __syncthreads();   // chunk 0 resident

    int buf = 0;
    for (int ch = 0; ch < NCH; ++ch) {
        // ---- issue next-chunk stage into buf^1 BEFORE computing ----
        if (ch + 1 < NCH) {
            const int kc = (ch + 1) << 6;
            const int nb = buf ^ 1;
            gld_lds16(x + (size_t)(t0 + xrow) * D_DIM + kc + xcg * 4,
                      &XF[nb][(wv * 64) * 4]);
            #pragma unroll
            for (int i2 = 0; i2 < 2; ++i2) {
                int e  = i2 * 32 + we;
                int og = wo ^ (e & 7);
                gld_lds16(WHg + (size_t)e * D_DIM + kc + og * 8,
                          &WHs[nb][(i2 * 256 + wv * 64) * 8]);
                gld_lds16(WLg + (size_t)e * D_DIM + kc + og * 8,
                          &WLs[nb][(i2 * 256 + wv * 64) * 8]);
            }
        }

        // ---- compute current buffer: 2 k-steps of 32 ----
        #pragma unroll
        for (int ks = 0; ks < 2; ++ks) {
            const int tr = l16;                           // token row
            const int c0 = ks * 8 + quad * 2;             // float4 col of k-window
            float4 xa = *(const float4*)&XF[buf][(tr * 16 + ( c0      ^ (tr & 15))) * 4];
            float4 xb = *(const float4*)&XF[buf][(tr * 16 + ((c0 + 1) ^ (tr & 15))) * 4];
            ushort4 h0, l0, h1, l1;
            split4(xa, &h0, &l0);
            split4(xb, &h1, &l1);
            union { us8 u; bf16x8 b; } ua, ul;
            ua.u = (us8){h0.x, h0.y, h0.z, h0.w, h1.x, h1.y, h1.z, h1.w};
            ul.u = (us8){l0.x, l0.y, l0.z, l0.w, l1.x, l1.y, l1.z, l1.w};

            const int e = wv * 16 + l16;
            const int o = ks * 4 + quad;
            const int s = e * 8 + (o ^ (e & 7));
            bf16x8 bh = *(const bf16x8*)&WHs[buf][s * 8];
            bf16x8 bl = *(const bf16x8*)&WLs[buf][s * 8];
            acc = __builtin_amdgcn_mfma_f32_16x16x32_bf16(ua.b, bh, acc, 0, 0, 0);
            acc = __builtin_amdgcn_mfma_f32_16x16x32_bf16(ul.b, bh, acc, 0, 0, 0);
            acc = __builtin_amdgcn_mfma_f32_16x16x32_bf16(ua.b, bl, acc, 0, 0, 0);
        }
        __syncthreads();   // all waves done reading buf; next stage resident
        buf ^= 1;
    }

    // ---- epilogue: exchange 16-expert slices via LDS, then 64-lane reduce ----
    // acc[r] = logit(token = quad*4 + r, expert = wv*16 + l16).
    // Safe to reuse XF[0]: last chunk (31) computed from XF[1].
    float* L = &XF[0][0];                      // [16 tokens][64 experts]
    #pragma unroll
    for (int r = 0; r < 4; ++r)
        L[(quad * 4 + r) * 64 + wv * 16 + l16] = acc[r];
    __syncthreads();

    for (int i = 0; i < 4; ++i) {
        const int tl = wv * 4 + i;             // token within block
        const int t  = t0 + tl;
        const float v = L[tl * 64 + lane];

        // argmax, lower-index tie-break (matches jax.lax.top_k)
        float bv = v; int bi = lane;
        #pragma unroll
        for (int off = 1; off < 64; off <<= 1) {
            float ov = __shfl_xor(bv, off, 64);
            int   oi = __shfl_xor(bi, off, 64);
            bool take = (ov > bv) || (ov == bv && oi < bi);
            bv = take ? ov : bv;
            bi = take ? oi : bi;
        }
        const float m = bv; const int i1 = bi;

        const float p = __expf(v - m);
        float s = p;
        #pragma unroll
        for (int off = 1; off < 64; off <<= 1) s += __shfl_xor(s, off, 64);
        const float prob = p / s;

        // second argmax excluding i1
        const float v2 = (lane == i1) ? -INFINITY : v;
        float cv = v2; int ci = lane;
        #pragma unroll
        for (int off = 1; off < 64; off <<= 1) {
            float ov = __shfl_xor(cv, off, 64);
            int   oi = __shfl_xor(ci, off, 64);
            bool take = (ov > cv) || (ov == cv && oi < ci);
            cv = take ? ov : cv;
            ci = take ? oi : ci;
        }
        const int i2 = ci;

        const float pd = __shfl(prob, i1, 64) + __shfl(prob, i2, 64);
        const bool top = (lane == i1) || (lane == i2);

        const size_t base = (size_t)t * 64 + lane;
        mask_out[base]  = top ? 1.f : 0.f;
        rp_out[base]    = top ? prob / pd : 0.f;
        probs_out[base] = prob;
        if (lane == 0) {
            idx_out[(size_t)t * 2]     = (float)i1;
            idx_out[(size_t)t * 2 + 1] = (float)i2;
        }
    }
}

extern "C" void kernel_launch(void* const* d_in, const int* in_sizes, int n_in,
                              void* d_out, int out_size, void* d_ws, size_t ws_size,
                              hipStream_t stream) {
    const float* x = (const float*)d_in[0];
    const float* W = (const float*)d_in[1];
    float* out = (float*)d_out;

    const int T  = in_sizes[0] / D_DIM;     // 16384 tokens
    const int WN = in_sizes[1];             // 131072 elements

    unsigned short* WH = (unsigned short*)d_ws;
    unsigned short* WL = WH + WN;           // total ws use: 512 KB

    float* mask_out  = out;
    float* idx_out   = out + (size_t)T * E_DIM;
    float* rp_out    = idx_out + (size_t)T * 2;
    float* probs_out = rp_out + (size_t)T * E_DIM;

    convert_w<<<dim3(WN / 1024), dim3(256), 0, stream>>>((const float4*)W, WH, WL);
    router_fused<<<dim3(T / 16), dim3(256), 0, stream>>>(
        x, WH, WL, mask_out, idx_out, rp_out, probs_out);
}

// Round 4
// 218.337 us; speedup vs baseline: 1.3242x; 1.0135x over previous
//
#include <hip/hip_runtime.h>
#include <math.h>

// MoE top-2 router. Round 7: counted-vmcnt pipeline + deduped x-conversion.
// Round 6 (16-token blocks, 4 blocks/CU) fixed occupancy but stayed at 84us:
// (a) __syncthreads() drains vmcnt(0), killing the prefetch every chunk;
// (b) all 4 waves re-split the same X tile (4x redundant VALU).
// Fix: raw s_barrier + s_waitcnt vmcnt(1) (W prefetch stays in flight across
// the barrier, m201 template); x is reg-staged per wave-quarter, split once,
// ds_written as bf16 hi/lo into XOR-swizzled LDS tiles read directly as MFMA
// A-fragments. LDS = 40KB exactly -> still 4 blocks/CU.
//
// x: [16384, 2048] fp32, W: [64, 2048] fp32.
// outputs (concat, fp32): mask [T,64], idx-as-float [T,2],
//                         router_probs [T,64], probs [T,64]

#define D_DIM 2048
#define E_DIM 64
#define NCH   (D_DIM >> 6)   // 32 chunks of 64 k

typedef __bf16 bf16x8 __attribute__((ext_vector_type(8)));
typedef unsigned short us8 __attribute__((ext_vector_type(8)));
typedef float f32x4 __attribute__((ext_vector_type(4)));

static __device__ __forceinline__ unsigned short f2bf(float f) {
    unsigned int u = __float_as_uint(f);
    u += 0x7fffu + ((u >> 16) & 1u);   // RNE
    return (unsigned short)(u >> 16);
}
static __device__ __forceinline__ float bf2f(unsigned short h) {
    return __uint_as_float(((unsigned int)h) << 16);
}
static __device__ __forceinline__ void split4(const float4 v, ushort4* h, ushort4* l) {
    h->x = f2bf(v.x); l->x = f2bf(v.x - bf2f(h->x));
    h->y = f2bf(v.y); l->y = f2bf(v.y - bf2f(h->y));
    h->z = f2bf(v.z); l->z = f2bf(v.z - bf2f(h->z));
    h->w = f2bf(v.w); l->w = f2bf(v.w - bf2f(h->w));
}

static __device__ __forceinline__ void gld_lds16(const void* g, void* l) {
    __builtin_amdgcn_global_load_lds(
        (const __attribute__((address_space(1))) unsigned int*)g,
        (__attribute__((address_space(3))) unsigned int*)l,
        16, 0, 0);
}

// ---- pre-convert W (64x2048 fp32) -> bf16 hi/lo, linear layout ----
__global__ __launch_bounds__(256, 1) void convert_w(
    const float4* __restrict__ W4, unsigned short* __restrict__ WH,
    unsigned short* __restrict__ WL)
{
    int i = blockIdx.x * 256 + threadIdx.x;   // float4 index
    float4 v = W4[i];
    ushort4 h, l;
    split4(v, &h, &l);
    *(ushort4*)&WH[i * 4] = h;
    *(ushort4*)&WL[i * 4] = l;
}

// ---- fused GEMM + softmax + top-2 + outputs ----
// block = 16 tokens x 64 experts x K=2048; 256 threads (4 waves);
// wave wv computes expert tile [wv*16, wv*16+16) for all 16 tokens.
__global__ __launch_bounds__(256, 4) void router_fused(
    const float* __restrict__ x,
    const unsigned short* __restrict__ WHg, const unsigned short* __restrict__ WLg,
    float* __restrict__ mask_out, float* __restrict__ idx_out,
    float* __restrict__ rp_out, float* __restrict__ probs_out)
{
    // bf16 x tiles (hi/lo), XOR-swizzled at 16B-slot level; W as round 6.
    __shared__ __align__(16) unsigned short XH [2][16 * 64];  // 2x 2 KB
    __shared__ __align__(16) unsigned short XL [2][16 * 64];  // 2x 2 KB
    __shared__ __align__(16) unsigned short WHs[2][64 * 64];  // 2x 8 KB
    __shared__ __align__(16) unsigned short WLs[2][64 * 64];  // 2x 8 KB
    // total 40 KB -> 4 blocks/CU

    const int tid  = threadIdx.x;
    const int lane = tid & 63;
    const int wv   = tid >> 6;
    const int quad = lane >> 4;
    const int l16  = lane & 15;

    const int t0 = blockIdx.x << 4;

    f32x4 acc = {0.f, 0.f, 0.f, 0.f};

    // W staging constants (round-6 verified)
    const int we = wv * 8 + (lane >> 3);             // + 32*i2 -> W expert row
    const int wo = lane & 7;                         // k-octet before swizzle

    // x: lane loads float4 at row (t0+l16), k = kc + wv*16 + quad*4.
    // (wave covers 16 contiguous k per row; 4 waves cover the 64-k chunk)
    const float* xg = x + (size_t)(t0 + l16) * D_DIM + wv * 16 + quad * 4;

    // convert ds_write byte offset: row l16, 8B granule g = wv*4+quad;
    // 16B slot = g>>1, swizzled ^= (row&7); low half by g&1.
    const int g   = wv * 4 + quad;
    const int cwb = l16 * 128 + (((g >> 1) ^ (l16 & 7)) << 4) + (g & 1) * 8;

    // ---- prologue: x chunk 0 to regs; W chunk 0 staged ----
    float4 xc = *(const float4*)(xg);
    #pragma unroll
    for (int i2 = 0; i2 < 2; ++i2) {
        int e  = i2 * 32 + we;
        int og = wo ^ (e & 7);
        gld_lds16(WHg + (size_t)e * D_DIM + og * 8, &WHs[0][(i2 * 256 + wv * 64) * 8]);
        gld_lds16(WLg + (size_t)e * D_DIM + og * 8, &WLs[0][(i2 * 256 + wv * 64) * 8]);
    }

    for (int ch = 0; ch < NCH; ++ch) {
        const int b = ch & 1;

        // issue next x load early (4 VGPRs in flight; compiler-tracked)
        float4 xn;
        if (ch + 1 < NCH) xn = *(const float4*)(xg + (ch + 1) * 64);

        // convert this chunk's x quarter -> swizzled bf16 hi/lo LDS
        {
            ushort4 h, l;
            split4(xc, &h, &l);
            *(ushort4*)((char*)&XH[b][0] + cwb) = h;
            *(ushort4*)((char*)&XL[b][0] + cwb) = l;
        }

        // drain own W_ch loads (leave x_{ch+1} in flight); own ds_writes visible
        if (ch + 1 < NCH) asm volatile("s_waitcnt vmcnt(1)" ::: "memory");
        else              asm volatile("s_waitcnt vmcnt(0)" ::: "memory");
        asm volatile("s_waitcnt lgkmcnt(0)" ::: "memory");
        __builtin_amdgcn_sched_barrier(0);
        __builtin_amdgcn_s_barrier();
        __builtin_amdgcn_sched_barrier(0);
        // after barrier: all waves' W_ch resident, all converts visible;
        // everyone finished compute(ch-1) -> safe to overwrite buf b^1.

        if (ch + 1 < NCH) {
            const int kc = (ch + 1) << 6;
            const int nb = b ^ 1;
            #pragma unroll
            for (int i2 = 0; i2 < 2; ++i2) {
                int e  = i2 * 32 + we;
                int og = wo ^ (e & 7);
                gld_lds16(WHg + (size_t)e * D_DIM + kc + og * 8,
                          &WHs[nb][(i2 * 256 + wv * 64) * 8]);
                gld_lds16(WLg + (size_t)e * D_DIM + kc + og * 8,
                          &WLs[nb][(i2 * 256 + wv * 64) * 8]);
            }
        }

        // ---- compute: 2 k-steps of 32 from bf16 tiles ----
        #pragma unroll
        for (int ks = 0; ks < 2; ++ks) {
            const int sr = ks * 4 + quad;                     // 16B slot in row
            const int ab = l16 * 128 + ((sr ^ (l16 & 7)) << 4);
            bf16x8 ah = *(const bf16x8*)((const char*)&XH[b][0] + ab);
            bf16x8 al = *(const bf16x8*)((const char*)&XL[b][0] + ab);

            const int e = wv * 16 + l16;
            const int o = ks * 4 + quad;
            const int s = e * 8 + (o ^ (e & 7));
            bf16x8 bh = *(const bf16x8*)&WHs[b][s * 8];
            bf16x8 bl = *(const bf16x8*)&WLs[b][s * 8];
            acc = __builtin_amdgcn_mfma_f32_16x16x32_bf16(ah, bh, acc, 0, 0, 0);
            acc = __builtin_amdgcn_mfma_f32_16x16x32_bf16(al, bh, acc, 0, 0, 0);
            acc = __builtin_amdgcn_mfma_f32_16x16x32_bf16(ah, bl, acc, 0, 0, 0);
        }

        if (ch + 1 < NCH) xc = xn;
    }

    // ---- epilogue: exchange 16-expert slices via LDS, then 64-lane reduce ----
    // acc[r] = logit(token = quad*4 + r, expert = wv*16 + l16).
    // Reuse WHs[0] (8 KB) as the 4 KB logits tile: last compute read buf b=1.
    float* L = (float*)&WHs[0][0];             // [16 tokens][64 experts]
    #pragma unroll
    for (int r = 0; r < 4; ++r)
        L[(quad * 4 + r) * 64 + wv * 16 + l16] = acc[r];
    __syncthreads();

    for (int i = 0; i < 4; ++i) {
        const int tl = wv * 4 + i;             // token within block
        const int t  = t0 + tl;
        const float v = L[tl * 64 + lane];

        // argmax, lower-index tie-break (matches jax.lax.top_k)
        float bv = v; int bi = lane;
        #pragma unroll
        for (int off = 1; off < 64; off <<= 1) {
            float ov = __shfl_xor(bv, off, 64);
            int   oi = __shfl_xor(bi, off, 64);
            bool take = (ov > bv) || (ov == bv && oi < bi);
            bv = take ? ov : bv;
            bi = take ? oi : bi;
        }
        const float m = bv; const int i1 = bi;

        const float p = __expf(v - m);
        float s = p;
        #pragma unroll
        for (int off = 1; off < 64; off <<= 1) s += __shfl_xor(s, off, 64);
        const float prob = p / s;

        // second argmax excluding i1
        const float v2 = (lane == i1) ? -INFINITY : v;
        float cv = v2; int ci = lane;
        #pragma unroll
        for (int off = 1; off < 64; off <<= 1) {
            float ov = __shfl_xor(cv, off, 64);
            int   oi = __shfl_xor(ci, off, 64);
            bool take = (ov > cv) || (ov == cv && oi < ci);
            cv = take ? ov : cv;
            ci = take ? oi : ci;
        }
        const int i2 = ci;

        const float pd = __shfl(prob, i1, 64) + __shfl(prob, i2, 64);
        const bool top = (lane == i1) || (lane == i2);

        const size_t base = (size_t)t * 64 + lane;
        mask_out[base]  = top ? 1.f : 0.f;
        rp_out[base]    = top ? prob / pd : 0.f;
        probs_out[base] = prob;
        if (lane == 0) {
            idx_out[(size_t)t * 2]     = (float)i1;
            idx_out[(size_t)t * 2 + 1] = (float)i2;
        }
    }
}

extern "C" void kernel_launch(void* const* d_in, const int* in_sizes, int n_in,
                              void* d_out, int out_size, void* d_ws, size_t ws_size,
                              hipStream_t stream) {
    const float* x = (const float*)d_in[0];
    const float* W = (const float*)d_in[1];
    float* out = (float*)d_out;

    const int T  = in_sizes[0] / D_DIM;     // 16384 tokens
    const int WN = in_sizes[1];             // 131072 elements

    unsigned short* WH = (unsigned short*)d_ws;
    unsigned short* WL = WH + WN;           // total ws use: 512 KB

    float* mask_out  = out;
    float* idx_out   = out + (size_t)T * E_DIM;
    float* rp_out    = idx_out + (size_t)T * 2;
    float* probs_out = rp_out + (size_t)T * E_DIM;

    convert_w<<<dim3(WN / 1024), dim3(256), 0, stream>>>((const float4*)W, WH, WL);
    router_fused<<<dim3(T / 16), dim3(256), 0, stream>>>(
        x, WH, WL, mask_out, idx_out, rp_out, probs_out);
}